// Round 1
// baseline (419.702 us; speedup 1.0000x reference)
//
#include <hip/hip_runtime.h>
#include <cstdint>

typedef __attribute__((ext_vector_type(8))) __bf16 bf16x8;
typedef __attribute__((ext_vector_type(4))) float f32x4;
typedef __attribute__((ext_vector_type(8))) unsigned short u16x8;
typedef __attribute__((ext_vector_type(4))) unsigned short u16x4;

__device__ __forceinline__ unsigned short f2bf(float f) {
    union { float f; unsigned u; } v; v.f = f;
    unsigned u = v.u;
    return (unsigned short)((u + 0x7FFFu + ((u >> 16) & 1u)) >> 16);
}

// CK-style addrspace cast via uintptr_t (low 32 bits of flat LDS addr == LDS offset)
__device__ __forceinline__ void gload_lds16(const void* g, void* l) {
    auto gp = reinterpret_cast<__attribute__((address_space(1))) unsigned*>(
        reinterpret_cast<uintptr_t>(g));
    auto lp = reinterpret_cast<__attribute__((address_space(3))) unsigned*>(
        reinterpret_cast<uintptr_t>(l));
    __builtin_amdgcn_global_load_lds(gp, lp, 16, 0, 0);
}

// ---------------- fp32 -> bf16 cast ----------------
__global__ __launch_bounds__(256) void cvt_kernel(const float* __restrict__ in,
                                                  unsigned short* __restrict__ out, int n4) {
    int idx = blockIdx.x * 256 + threadIdx.x;
    int stride = gridDim.x * 256;
    for (int i = idx; i < n4; i += stride) {
        float4 v = ((const float4*)in)[i];
        u16x4 o;
        o.x = f2bf(v.x); o.y = f2bf(v.y); o.z = f2bf(v.z); o.w = f2bf(v.w);
        ((u16x4*)out)[i] = o;
    }
}

// ---------------- fp32 [R][C] -> bf16 [C][R] ----------------
__global__ __launch_bounds__(256) void transpose_cvt(const float* __restrict__ in,
                                                     unsigned short* __restrict__ out,
                                                     int R, int C) {
    __shared__ float t[32][33];
    int c0 = blockIdx.x * 32, r0 = blockIdx.y * 32;
    int tx = threadIdx.x, ty = threadIdx.y;
    for (int i = ty; i < 32; i += 8)
        t[i][tx] = in[(size_t)(r0 + i) * C + c0 + tx];
    __syncthreads();
    for (int i = ty; i < 32; i += 8)
        out[(size_t)(c0 + i) * R + r0 + tx] = f2bf(t[tx][i]);
}

// ---------------- bf16 GEMM: C[M][N] = A[M][K] @ Bt[N][K]^T, m97 structure ----------------
// 128x128 tile, BK=32, 4 waves (2x2), per-wave 4x4 of 16x16x32 MFMA.
__global__ __launch_bounds__(256) void gemm_bf16(const unsigned short* __restrict__ A,
                                                 const unsigned short* __restrict__ Bt,
                                                 void* __restrict__ C,
                                                 const float* __restrict__ bias,
                                                 int M, int N, int K, float scale, int c_f32) {
    __shared__ unsigned short lds_a[128 * 32];
    __shared__ unsigned short lds_b[128 * 32];
    int ntx = N >> 7;
    int nwg = gridDim.x;
    int bid = blockIdx.x;
    int swz = bid;
    if ((nwg & 7) == 0) { int cpx = nwg >> 3; swz = (bid & 7) * cpx + (bid >> 3); }
    int mt0 = swz / ntx, nt0 = swz % ntx;
    int m0 = mt0 << 7, n0 = nt0 << 7;
    int tid = threadIdx.x;
    int lane = tid & 63, w = tid >> 6;
    int wm = w >> 1, wn = w & 1;
    int lr = lane & 15, lg = lane >> 4;
    f32x4 acc[4][4] = {};

    int arow = tid >> 2;
    int aseg = (tid & 3) << 3;  // element offset 0,8,16,24
    int ra0 = m0 + arow;       if (ra0 > M - 1) ra0 = M - 1;
    int ra1 = m0 + 64 + arow;  if (ra1 > M - 1) ra1 = M - 1;
    const unsigned short* a0p = A + (size_t)ra0 * K + aseg;
    const unsigned short* a1p = A + (size_t)ra1 * K + aseg;
    const unsigned short* b0p = Bt + (size_t)(n0 + arow) * K + aseg;
    const unsigned short* b1p = Bt + (size_t)(n0 + 64 + arow) * K + aseg;
    unsigned short* la = lds_a + (w << 9);  // wave-uniform base, lane*16B auto
    unsigned short* lb = lds_b + (w << 9);

    for (int k0 = 0; k0 < K; k0 += 32) {
        gload_lds16(a0p + k0, la);
        gload_lds16(a1p + k0, la + 2048);
        gload_lds16(b0p + k0, lb);
        gload_lds16(b1p + k0, lb + 2048);
        __syncthreads();
        bf16x8 af[4], bfr[4];
#pragma unroll
        for (int mt = 0; mt < 4; mt++)
            af[mt] = *(const bf16x8*)(lds_a + (size_t)((wm << 6) + (mt << 4) + lr) * 32 + (lg << 3));
#pragma unroll
        for (int nt = 0; nt < 4; nt++)
            bfr[nt] = *(const bf16x8*)(lds_b + (size_t)((wn << 6) + (nt << 4) + lr) * 32 + (lg << 3));
#pragma unroll
        for (int mt = 0; mt < 4; mt++)
#pragma unroll
            for (int nt = 0; nt < 4; nt++)
                acc[mt][nt] = __builtin_amdgcn_mfma_f32_16x16x32_bf16(af[mt], bfr[nt], acc[mt][nt], 0, 0, 0);
        __syncthreads();
    }
#pragma unroll
    for (int mt = 0; mt < 4; mt++) {
#pragma unroll
        for (int nt = 0; nt < 4; nt++) {
            int col = n0 + (wn << 6) + (nt << 4) + lr;
            float bv = bias ? bias[col] : 0.0f;
#pragma unroll
            for (int r = 0; r < 4; r++) {
                int row = m0 + (wm << 6) + (mt << 4) + (lg << 2) + r;
                if (row < M) {
                    float v = acc[mt][nt][r] * scale + bv;
                    if (c_f32) ((float*)C)[(size_t)row * N + col] = v;
                    else       ((unsigned short*)C)[(size_t)row * N + col] = f2bf(v);
                }
            }
        }
    }
}

// ---------------- fused flash attention over 1088 keys (1024 media + 64 latent) ----------------
// grid 512 = (bm, h); 4 waves, wave w owns q-rows [16w,16w+16); 17 j-tiles of 64.
__global__ __launch_bounds__(256) void attn_kernel(const unsigned short* __restrict__ qg,
                                                   const unsigned short* __restrict__ kvg,
                                                   const unsigned short* __restrict__ lkvg,
                                                   unsigned short* __restrict__ og) {
    __shared__ unsigned short K_lds[64 * 72];      // [j][dh], stride 72 keeps 16B align, 2-way banks
    __shared__ unsigned short V_lds[64 * 72];      // transposed: [dh][j]
    __shared__ unsigned short P_lds[4][16 * 72];   // per-wave P tile [i][j]
    int bm = blockIdx.x >> 4, h = blockIdx.x & 15;
    int tid = threadIdx.x, lane = tid & 63, w = tid >> 6;
    int lr = lane & 15, lg = lane >> 4;

    bf16x8 qf[2];
#pragma unroll
    for (int kk = 0; kk < 2; kk++)
        qf[kk] = *(const bf16x8*)(qg + (size_t)((w << 4) + lr) * 1024 + (h << 6) + (kk << 5) + (lg << 3));

    f32x4 acc[4] = {};
    float m_run[4], l_run[4];
#pragma unroll
    for (int r = 0; r < 4; r++) { m_run[r] = -1e30f; l_run[r] = 0.0f; }

    int jrow = tid >> 2;
    int seg = (tid & 3) << 4;  // 0,16,32,48

    for (int t = 0; t < 17; t++) {
        const unsigned short* src = (t < 16)
            ? kvg + (size_t)((bm << 10) + (t << 6) + jrow) * 2048 + (h << 6)
            : lkvg + (size_t)jrow * 2048 + (h << 6);
        u16x8 k0 = *(const u16x8*)(src + seg);
        u16x8 k1 = *(const u16x8*)(src + seg + 8);
        u16x8 v0 = *(const u16x8*)(src + 1024 + seg);
        u16x8 v1 = *(const u16x8*)(src + 1024 + seg + 8);
        *(u16x8*)(&K_lds[jrow * 72 + seg]) = k0;
        *(u16x8*)(&K_lds[jrow * 72 + seg + 8]) = k1;
#pragma unroll
        for (int c = 0; c < 8; c++) V_lds[(seg + c) * 72 + jrow] = v0[c];
#pragma unroll
        for (int c = 0; c < 8; c++) V_lds[(seg + 8 + c) * 72 + jrow] = v1[c];
        __syncthreads();

        f32x4 s[4] = {};
#pragma unroll
        for (int jt = 0; jt < 4; jt++) {
#pragma unroll
            for (int kk = 0; kk < 2; kk++) {
                bf16x8 kf = *(const bf16x8*)(&K_lds[(size_t)((jt << 4) + lr) * 72 + (kk << 5) + (lg << 3)]);
                s[jt] = __builtin_amdgcn_mfma_f32_16x16x32_bf16(qf[kk], kf, s[jt], 0, 0, 0);
            }
        }
        // online softmax: rows 4*lg+r, cols 16*jt+lr; reduce across the 16-lane group
#pragma unroll
        for (int r = 0; r < 4; r++) {
            float mx = fmaxf(fmaxf(s[0][r], s[1][r]), fmaxf(s[2][r], s[3][r]));
            mx = fmaxf(mx, __shfl_xor(mx, 1));
            mx = fmaxf(mx, __shfl_xor(mx, 2));
            mx = fmaxf(mx, __shfl_xor(mx, 4));
            mx = fmaxf(mx, __shfl_xor(mx, 8));
            float nm = fmaxf(m_run[r], mx);
            float fct = __expf(m_run[r] - nm);
            m_run[r] = nm;
            float p0 = __expf(s[0][r] - nm);
            float p1 = __expf(s[1][r] - nm);
            float p2 = __expf(s[2][r] - nm);
            float p3 = __expf(s[3][r] - nm);
            float sum = p0 + p1 + p2 + p3;
            sum += __shfl_xor(sum, 1);
            sum += __shfl_xor(sum, 2);
            sum += __shfl_xor(sum, 4);
            sum += __shfl_xor(sum, 8);
            l_run[r] = l_run[r] * fct + sum;
#pragma unroll
            for (int dt = 0; dt < 4; dt++) acc[dt][r] *= fct;
            int prow = ((lg << 2) + r) * 72;
            P_lds[w][prow + lr]      = f2bf(p0);
            P_lds[w][prow + 16 + lr] = f2bf(p1);
            P_lds[w][prow + 32 + lr] = f2bf(p2);
            P_lds[w][prow + 48 + lr] = f2bf(p3);
        }
        // PV: acc[dt] += P(16x64) @ V(64x64)
#pragma unroll
        for (int jkk = 0; jkk < 2; jkk++) {
            bf16x8 pf = *(const bf16x8*)(&P_lds[w][(size_t)lr * 72 + (jkk << 5) + (lg << 3)]);
#pragma unroll
            for (int dt = 0; dt < 4; dt++) {
                bf16x8 vf = *(const bf16x8*)(&V_lds[(size_t)((dt << 4) + lr) * 72 + (jkk << 5) + (lg << 3)]);
                acc[dt] = __builtin_amdgcn_mfma_f32_16x16x32_bf16(pf, vf, acc[dt], 0, 0, 0);
            }
        }
        __syncthreads();
    }
#pragma unroll
    for (int dt = 0; dt < 4; dt++) {
#pragma unroll
        for (int r = 0; r < 4; r++) {
            int i = (w << 4) + (lg << 2) + r;
            float v = acc[dt][r] / l_run[r];
            og[(size_t)((bm << 6) + i) * 1024 + (h << 6) + (dt << 4) + lr] = f2bf(v);
        }
    }
}

extern "C" void kernel_launch(void* const* d_in, const int* in_sizes, int n_in,
                              void* d_out, int out_size, void* d_ws, size_t ws_size,
                              hipStream_t stream) {
    const float* x       = (const float*)d_in[0];
    const float* latents = (const float*)d_in[1];
    const float* Wq      = (const float*)d_in[2];
    const float* Wkv     = (const float*)d_in[3];
    const float* Wout    = (const float*)d_in[4];
    const float* bout    = (const float*)d_in[5];
    char* ws = (char*)d_ws;
    unsigned short* xb    = (unsigned short*)(ws);                 // 64 MiB  [32768][1024]
    unsigned short* kvb   = (unsigned short*)(ws + 67108864);      // 128 MiB [32768][2048]
    unsigned short* wqt   = (unsigned short*)(ws + 201326592);     // 2 MiB   [1024][1024] (N,K)
    unsigned short* wkvt  = (unsigned short*)(ws + 203423744);     // 4 MiB   [2048][1024]
    unsigned short* woutt = (unsigned short*)(ws + 207618048);     // 2 MiB   [1024][1024]
    unsigned short* latb  = (unsigned short*)(ws + 209715200);     // 128 KiB [64][1024]
    unsigned short* qb    = (unsigned short*)(ws + 209846272);     // 128 KiB [64][1024]
    unsigned short* lkvb  = (unsigned short*)(ws + 209977344);     // 256 KiB [64][2048]
    unsigned short* attnb = (unsigned short*)(ws + 210239488);     // 4 MiB   [2048][1024]

    cvt_kernel<<<2048, 256, 0, stream>>>(x, xb, 33554432 / 4);
    cvt_kernel<<<64, 256, 0, stream>>>(latents, latb, 65536 / 4);
    dim3 tb(32, 8);
    transpose_cvt<<<dim3(32, 32), tb, 0, stream>>>(Wq, wqt, 1024, 1024);
    transpose_cvt<<<dim3(64, 32), tb, 0, stream>>>(Wkv, wkvt, 1024, 2048);
    transpose_cvt<<<dim3(32, 32), tb, 0, stream>>>(Wout, woutt, 1024, 1024);
    // q = latents @ Wq * dh^-0.5  (rows >= 64 are padding, masked on store)
    gemm_bf16<<<8, 256, 0, stream>>>(latb, wqt, qb, nullptr, 64, 1024, 1024, 0.125f, 0);
    // lkv = latents @ Wkv
    gemm_bf16<<<16, 256, 0, stream>>>(latb, wkvt, lkvb, nullptr, 64, 2048, 1024, 1.0f, 0);
    // kv = x @ Wkv   (dominant GEMM)
    gemm_bf16<<<4096, 256, 0, stream>>>(xb, wkvt, kvb, nullptr, 32768, 2048, 1024, 1.0f, 0);
    // fused attention
    attn_kernel<<<512, 256, 0, stream>>>(qb, kvb, lkvb, attnb);
    // out = attnout @ Wout + bout (fp32 out)
    gemm_bf16<<<128, 256, 0, stream>>>(attnb, woutt, (void*)d_out, bout, 2048, 1024, 1024, 1.0f, 1);
}

// Round 2
// 318.262 us; speedup vs baseline: 1.3187x; 1.3187x over previous
//
#include <hip/hip_runtime.h>
#include <cstdint>

typedef __attribute__((ext_vector_type(8))) __bf16 bf16x8;
typedef __attribute__((ext_vector_type(4))) float f32x4;
typedef __attribute__((ext_vector_type(8))) unsigned short u16x8;
typedef __attribute__((ext_vector_type(4))) unsigned short u16x4;

__device__ __forceinline__ unsigned short f2bf(float f) {
    union { float f; unsigned u; } v; v.f = f;
    unsigned u = v.u;
    return (unsigned short)((u + 0x7FFFu + ((u >> 16) & 1u)) >> 16);
}

__device__ __forceinline__ void gload_lds16(const void* g, void* l) {
    auto gp = reinterpret_cast<__attribute__((address_space(1))) unsigned*>(
        reinterpret_cast<uintptr_t>(g));
    auto lp = reinterpret_cast<__attribute__((address_space(3))) unsigned*>(
        reinterpret_cast<uintptr_t>(l));
    __builtin_amdgcn_global_load_lds(gp, lp, 16, 0, 0);
}

// ---------------- fp32 -> bf16 cast ----------------
__global__ __launch_bounds__(256) void cvt_kernel(const float* __restrict__ in,
                                                  unsigned short* __restrict__ out, int n4) {
    int idx = blockIdx.x * 256 + threadIdx.x;
    int stride = gridDim.x * 256;
    for (int i = idx; i < n4; i += stride) {
        float4 v = ((const float4*)in)[i];
        u16x4 o;
        o.x = f2bf(v.x); o.y = f2bf(v.y); o.z = f2bf(v.z); o.w = f2bf(v.w);
        ((u16x4*)out)[i] = o;
    }
}

// ---------------- fp32 [R][C] -> bf16 [C][R] ----------------
__global__ __launch_bounds__(256) void transpose_cvt(const float* __restrict__ in,
                                                     unsigned short* __restrict__ out,
                                                     int R, int C) {
    __shared__ float t[32][33];
    int c0 = blockIdx.x * 32, r0 = blockIdx.y * 32;
    int tx = threadIdx.x, ty = threadIdx.y;
    for (int i = ty; i < 32; i += 8)
        t[i][tx] = in[(size_t)(r0 + i) * C + c0 + tx];
    __syncthreads();
    for (int i = ty; i < 32; i += 8)
        out[(size_t)(c0 + i) * R + r0 + tx] = f2bf(t[tx][i]);
}

// ---------------- small/medium bf16 GEMM (m97 structure, 128x128 tile) ----------------
__global__ __launch_bounds__(256) void gemm_bf16(const unsigned short* __restrict__ A,
                                                 const unsigned short* __restrict__ Bt,
                                                 void* __restrict__ C,
                                                 const float* __restrict__ bias,
                                                 int M, int N, int K, float scale, int c_f32) {
    __shared__ unsigned short lds_a[128 * 32];
    __shared__ unsigned short lds_b[128 * 32];
    int ntx = N >> 7;
    int nwg = gridDim.x;
    int bid = blockIdx.x;
    int swz = bid;
    if ((nwg & 7) == 0) { int cpx = nwg >> 3; swz = (bid & 7) * cpx + (bid >> 3); }
    int mt0 = swz / ntx, nt0 = swz % ntx;
    int m0 = mt0 << 7, n0 = nt0 << 7;
    int tid = threadIdx.x;
    int lane = tid & 63, w = tid >> 6;
    int wm = w >> 1, wn = w & 1;
    int lr = lane & 15, lg = lane >> 4;
    f32x4 acc[4][4] = {};

    int arow = tid >> 2;
    int aseg = (tid & 3) << 3;
    int ra0 = m0 + arow;       if (ra0 > M - 1) ra0 = M - 1;
    int ra1 = m0 + 64 + arow;  if (ra1 > M - 1) ra1 = M - 1;
    const unsigned short* a0p = A + (size_t)ra0 * K + aseg;
    const unsigned short* a1p = A + (size_t)ra1 * K + aseg;
    const unsigned short* b0p = Bt + (size_t)(n0 + arow) * K + aseg;
    const unsigned short* b1p = Bt + (size_t)(n0 + 64 + arow) * K + aseg;
    unsigned short* la = lds_a + (w << 9);
    unsigned short* lb = lds_b + (w << 9);

    for (int k0 = 0; k0 < K; k0 += 32) {
        gload_lds16(a0p + k0, la);
        gload_lds16(a1p + k0, la + 2048);
        gload_lds16(b0p + k0, lb);
        gload_lds16(b1p + k0, lb + 2048);
        __syncthreads();
        bf16x8 af[4], bfr[4];
#pragma unroll
        for (int mt = 0; mt < 4; mt++)
            af[mt] = *(const bf16x8*)(lds_a + (size_t)((wm << 6) + (mt << 4) + lr) * 32 + (lg << 3));
#pragma unroll
        for (int nt = 0; nt < 4; nt++)
            bfr[nt] = *(const bf16x8*)(lds_b + (size_t)((wn << 6) + (nt << 4) + lr) * 32 + (lg << 3));
#pragma unroll
        for (int mt = 0; mt < 4; mt++)
#pragma unroll
            for (int nt = 0; nt < 4; nt++)
                acc[mt][nt] = __builtin_amdgcn_mfma_f32_16x16x32_bf16(af[mt], bfr[nt], acc[mt][nt], 0, 0, 0);
        __syncthreads();
    }
#pragma unroll
    for (int mt = 0; mt < 4; mt++) {
#pragma unroll
        for (int nt = 0; nt < 4; nt++) {
            int col = n0 + (wn << 6) + (nt << 4) + lr;
            float bv = bias ? bias[col] : 0.0f;
#pragma unroll
            for (int r = 0; r < 4; r++) {
                int row = m0 + (wm << 6) + (mt << 4) + (lg << 2) + r;
                if (row < M) {
                    float v = acc[mt][nt][r] * scale + bv;
                    if (c_f32) ((float*)C)[(size_t)row * N + col] = v;
                    else       ((unsigned short*)C)[(size_t)row * N + col] = f2bf(v);
                }
            }
        }
    }
}

// ---------------- large bf16 GEMM: 256x256 tile, triple-buffered counted-vmcnt pipeline ----------------
// C[M][N] = A[M][K] @ Bt[N][K]^T. Requires M%256==0, N%256==0, K%32==0, K>=96.
// 8 waves (2x4), per-wave 128x64 output. LDS: 3 bufs x (A,B) planes of [256][32] bf16.
// Swizzle: phys granule = logical granule ^ ((row>>1)&3)  (granule = 8 bf16 = 16B).
// Schedule per K-tile: vmcnt(4); s_barrier; stage A(t+2); read A-lo + B; 16 MFMA;
//                      stage B(t+2); read A-hi; 16 MFMA.  (never drains vmcnt to 0)
__global__ __launch_bounds__(512, 2) void gemm256(const unsigned short* __restrict__ A,
                                                  const unsigned short* __restrict__ Bt,
                                                  unsigned short* __restrict__ C,
                                                  int M, int N, int K) {
    __shared__ unsigned short lds[3][2][8192];  // 96 KiB
    int nkt = K >> 5;
    int ntx = N >> 8;
    int nwg = gridDim.x;
    int bid = blockIdx.x;
    int swz = bid;
    if ((nwg & 7) == 0) { int cpx = nwg >> 3; swz = (bid & 7) * cpx + (bid >> 3); }
    int m0 = (swz / ntx) << 8, n0 = (swz % ntx) << 8;
    int tid = threadIdx.x, lane = tid & 63, w = tid >> 6;
    int wm = w >> 2, wn = w & 3;
    int lr = lane & 15, lg = lane >> 4;
    int gq = lg ^ ((lr >> 1) & 3);  // phys granule for reads (same for every fragment row)

    // staging: thread covers LDS bytes j*8192 + tid*16 (j=0,1) per plane
    // -> row = j*128 + tid/4, phys granule = tid&3, logical granule = (tid&3)^((row>>1)&3)
    int srow = tid >> 2;
    int sgl = (tid & 3) ^ ((srow >> 1) & 3);  // (row+128)>>1 has same &3 -> same for j=1
    const unsigned short* a0 = A + (size_t)(m0 + srow) * K + (sgl << 3);
    const unsigned short* a1 = A + (size_t)(m0 + 128 + srow) * K + (sgl << 3);
    const unsigned short* b0 = Bt + (size_t)(n0 + srow) * K + (sgl << 3);
    const unsigned short* b1 = Bt + (size_t)(n0 + 128 + srow) * K + (sgl << 3);

    f32x4 acc[8][4] = {};

#define STAGE_A256(bufi, kt) do { \
        gload_lds16(a0 + ((kt) << 5), &lds[bufi][0][w << 9]); \
        gload_lds16(a1 + ((kt) << 5), &lds[bufi][0][4096 + (w << 9)]); } while (0)
#define STAGE_B256(bufi, kt) do { \
        gload_lds16(b0 + ((kt) << 5), &lds[bufi][1][w << 9]); \
        gload_lds16(b1 + ((kt) << 5), &lds[bufi][1][4096 + (w << 9)]); } while (0)

    // prologue: tiles 0 and 1
    STAGE_A256(0, 0); STAGE_B256(0, 0);
    STAGE_A256(1, 1); STAGE_B256(1, 1);

    int buf = 0;
    for (int t = 0; t < nkt; ++t) {
        asm volatile("s_waitcnt vmcnt(4)" ::: "memory");
        __builtin_amdgcn_s_barrier();
        int st = t + 2; if (st >= nkt) st = nkt - 1;  // clamp keeps vmcnt counts uniform
        int sbuf = buf + 2; if (sbuf >= 3) sbuf -= 3;

        const unsigned short* pa = &lds[buf][0][((wm << 7) + lr) * 32 + (gq << 3)];
        const unsigned short* pb = &lds[buf][1][((wn << 6) + lr) * 32 + (gq << 3)];

        // phase 1: stage A(t+2), read B (held in regs) + A rows 0..63 of wave half, 16 MFMA
        STAGE_A256(sbuf, st);
        bf16x8 bfr[4];
#pragma unroll
        for (int nt = 0; nt < 4; nt++) bfr[nt] = *(const bf16x8*)(pb + nt * 512);
        bf16x8 af[4];
#pragma unroll
        for (int mt = 0; mt < 4; mt++) af[mt] = *(const bf16x8*)(pa + mt * 512);
        __builtin_amdgcn_s_setprio(1);
#pragma unroll
        for (int mt = 0; mt < 4; mt++)
#pragma unroll
            for (int nt = 0; nt < 4; nt++)
                acc[mt][nt] = __builtin_amdgcn_mfma_f32_16x16x32_bf16(af[mt], bfr[nt], acc[mt][nt], 0, 0, 0);
        __builtin_amdgcn_s_setprio(0);

        // phase 2: stage B(t+2), read A rows 64..127 of wave half, 16 MFMA
        STAGE_B256(sbuf, st);
#pragma unroll
        for (int mt = 0; mt < 4; mt++) af[mt] = *(const bf16x8*)(pa + (mt + 4) * 512);
        __builtin_amdgcn_s_setprio(1);
#pragma unroll
        for (int mt = 0; mt < 4; mt++)
#pragma unroll
            for (int nt = 0; nt < 4; nt++)
                acc[mt + 4][nt] = __builtin_amdgcn_mfma_f32_16x16x32_bf16(af[mt], bfr[nt], acc[mt + 4][nt], 0, 0, 0);
        __builtin_amdgcn_s_setprio(0);

        buf++; if (buf == 3) buf = 0;
    }
#undef STAGE_A256
#undef STAGE_B256

#pragma unroll
    for (int mt = 0; mt < 8; mt++) {
#pragma unroll
        for (int nt = 0; nt < 4; nt++) {
            int col = n0 + (wn << 6) + (nt << 4) + lr;
            size_t rbase = (size_t)(m0 + (wm << 7) + (mt << 4) + (lg << 2));
#pragma unroll
            for (int r = 0; r < 4; r++)
                C[(rbase + r) * N + col] = f2bf(acc[mt][nt][r]);
        }
    }
}

// ---------------- fused flash attention over 1088 keys (1024 media + 64 latent) ----------------
__global__ __launch_bounds__(256) void attn_kernel(const unsigned short* __restrict__ qg,
                                                   const unsigned short* __restrict__ kvg,
                                                   const unsigned short* __restrict__ lkvg,
                                                   unsigned short* __restrict__ og) {
    __shared__ unsigned short K_lds[64 * 72];
    __shared__ unsigned short V_lds[64 * 72];
    __shared__ unsigned short P_lds[4][16 * 72];
    int bm = blockIdx.x >> 4, h = blockIdx.x & 15;
    int tid = threadIdx.x, lane = tid & 63, w = tid >> 6;
    int lr = lane & 15, lg = lane >> 4;

    bf16x8 qf[2];
#pragma unroll
    for (int kk = 0; kk < 2; kk++)
        qf[kk] = *(const bf16x8*)(qg + (size_t)((w << 4) + lr) * 1024 + (h << 6) + (kk << 5) + (lg << 3));

    f32x4 acc[4] = {};
    float m_run[4], l_run[4];
#pragma unroll
    for (int r = 0; r < 4; r++) { m_run[r] = -1e30f; l_run[r] = 0.0f; }

    int jrow = tid >> 2;
    int seg = (tid & 3) << 4;

    for (int t = 0; t < 17; t++) {
        const unsigned short* src = (t < 16)
            ? kvg + (size_t)((bm << 10) + (t << 6) + jrow) * 2048 + (h << 6)
            : lkvg + (size_t)jrow * 2048 + (h << 6);
        u16x8 k0 = *(const u16x8*)(src + seg);
        u16x8 k1 = *(const u16x8*)(src + seg + 8);
        u16x8 v0 = *(const u16x8*)(src + 1024 + seg);
        u16x8 v1 = *(const u16x8*)(src + 1024 + seg + 8);
        *(u16x8*)(&K_lds[jrow * 72 + seg]) = k0;
        *(u16x8*)(&K_lds[jrow * 72 + seg + 8]) = k1;
#pragma unroll
        for (int c = 0; c < 8; c++) V_lds[(seg + c) * 72 + jrow] = v0[c];
#pragma unroll
        for (int c = 0; c < 8; c++) V_lds[(seg + 8 + c) * 72 + jrow] = v1[c];
        __syncthreads();

        f32x4 s[4] = {};
#pragma unroll
        for (int jt = 0; jt < 4; jt++) {
#pragma unroll
            for (int kk = 0; kk < 2; kk++) {
                bf16x8 kf = *(const bf16x8*)(&K_lds[(size_t)((jt << 4) + lr) * 72 + (kk << 5) + (lg << 3)]);
                s[jt] = __builtin_amdgcn_mfma_f32_16x16x32_bf16(qf[kk], kf, s[jt], 0, 0, 0);
            }
        }
#pragma unroll
        for (int r = 0; r < 4; r++) {
            float mx = fmaxf(fmaxf(s[0][r], s[1][r]), fmaxf(s[2][r], s[3][r]));
            mx = fmaxf(mx, __shfl_xor(mx, 1));
            mx = fmaxf(mx, __shfl_xor(mx, 2));
            mx = fmaxf(mx, __shfl_xor(mx, 4));
            mx = fmaxf(mx, __shfl_xor(mx, 8));
            float nm = fmaxf(m_run[r], mx);
            float fct = __expf(m_run[r] - nm);
            m_run[r] = nm;
            float p0 = __expf(s[0][r] - nm);
            float p1 = __expf(s[1][r] - nm);
            float p2 = __expf(s[2][r] - nm);
            float p3 = __expf(s[3][r] - nm);
            float sum = p0 + p1 + p2 + p3;
            sum += __shfl_xor(sum, 1);
            sum += __shfl_xor(sum, 2);
            sum += __shfl_xor(sum, 4);
            sum += __shfl_xor(sum, 8);
            l_run[r] = l_run[r] * fct + sum;
#pragma unroll
            for (int dt = 0; dt < 4; dt++) acc[dt][r] *= fct;
            int prow = ((lg << 2) + r) * 72;
            P_lds[w][prow + lr]      = f2bf(p0);
            P_lds[w][prow + 16 + lr] = f2bf(p1);
            P_lds[w][prow + 32 + lr] = f2bf(p2);
            P_lds[w][prow + 48 + lr] = f2bf(p3);
        }
#pragma unroll
        for (int jkk = 0; jkk < 2; jkk++) {
            bf16x8 pf = *(const bf16x8*)(&P_lds[w][(size_t)lr * 72 + (jkk << 5) + (lg << 3)]);
#pragma unroll
            for (int dt = 0; dt < 4; dt++) {
                bf16x8 vf = *(const bf16x8*)(&V_lds[(size_t)((dt << 4) + lr) * 72 + (jkk << 5) + (lg << 3)]);
                acc[dt] = __builtin_amdgcn_mfma_f32_16x16x32_bf16(pf, vf, acc[dt], 0, 0, 0);
            }
        }
        __syncthreads();
    }
#pragma unroll
    for (int dt = 0; dt < 4; dt++) {
#pragma unroll
        for (int r = 0; r < 4; r++) {
            int i = (w << 4) + (lg << 2) + r;
            float v = acc[dt][r] / l_run[r];
            og[(size_t)((bm << 6) + i) * 1024 + (h << 6) + (dt << 4) + lr] = f2bf(v);
        }
    }
}

extern "C" void kernel_launch(void* const* d_in, const int* in_sizes, int n_in,
                              void* d_out, int out_size, void* d_ws, size_t ws_size,
                              hipStream_t stream) {
    const float* x       = (const float*)d_in[0];
    const float* latents = (const float*)d_in[1];
    const float* Wq      = (const float*)d_in[2];
    const float* Wkv     = (const float*)d_in[3];
    const float* Wout    = (const float*)d_in[4];
    const float* bout    = (const float*)d_in[5];
    char* ws = (char*)d_ws;
    unsigned short* xb    = (unsigned short*)(ws);                 // 64 MiB  [32768][1024]
    unsigned short* kvb   = (unsigned short*)(ws + 67108864);      // 128 MiB [32768][2048]
    unsigned short* wqt   = (unsigned short*)(ws + 201326592);     // 2 MiB   [1024][1024] (N,K)
    unsigned short* wkvt  = (unsigned short*)(ws + 203423744);     // 4 MiB   [2048][1024]
    unsigned short* woutt = (unsigned short*)(ws + 207618048);     // 2 MiB   [1024][1024]
    unsigned short* latb  = (unsigned short*)(ws + 209715200);     // 128 KiB [64][1024]
    unsigned short* qb    = (unsigned short*)(ws + 209846272);     // 128 KiB [64][1024]
    unsigned short* lkvb  = (unsigned short*)(ws + 209977344);     // 256 KiB [64][2048]
    unsigned short* attnb = (unsigned short*)(ws + 210239488);     // 4 MiB   [2048][1024]

    cvt_kernel<<<2048, 256, 0, stream>>>(x, xb, 33554432 / 4);
    cvt_kernel<<<64, 256, 0, stream>>>(latents, latb, 65536 / 4);
    dim3 tb(32, 8);
    transpose_cvt<<<dim3(32, 32), tb, 0, stream>>>(Wq, wqt, 1024, 1024);
    transpose_cvt<<<dim3(64, 32), tb, 0, stream>>>(Wkv, wkvt, 1024, 2048);
    transpose_cvt<<<dim3(32, 32), tb, 0, stream>>>(Wout, woutt, 1024, 1024);
    // q = latents @ Wq * dh^-0.5
    gemm_bf16<<<8, 256, 0, stream>>>(latb, wqt, qb, nullptr, 64, 1024, 1024, 0.125f, 0);
    // lkv = latents @ Wkv
    gemm_bf16<<<16, 256, 0, stream>>>(latb, wkvt, lkvb, nullptr, 64, 2048, 1024, 1.0f, 0);
    // kv = x @ Wkv  (dominant GEMM -> 256^2 pipelined kernel)
    gemm256<<<1024, 512, 0, stream>>>(xb, wkvt, kvb, 32768, 2048, 1024);
    // fused attention
    attn_kernel<<<512, 256, 0, stream>>>(qb, kvb, lkvb, attnb);
    // out = attnout @ Wout + bout (fp32 out)
    gemm_bf16<<<128, 256, 0, stream>>>(attnb, woutt, (void*)d_out, bout, 2048, 1024, 1024, 1.0f, 1);
}

// Round 3
// 271.038 us; speedup vs baseline: 1.5485x; 1.1742x over previous
//
#include <hip/hip_runtime.h>
#include <cstdint>

typedef __attribute__((ext_vector_type(8))) __bf16 bf16x8;
typedef __attribute__((ext_vector_type(4))) float f32x4;
typedef __attribute__((ext_vector_type(8))) unsigned short u16x8;
typedef __attribute__((ext_vector_type(4))) unsigned short u16x4;

__device__ __forceinline__ unsigned short f2bf(float f) {
    union { float f; unsigned u; } v; v.f = f;
    unsigned u = v.u;
    return (unsigned short)((u + 0x7FFFu + ((u >> 16) & 1u)) >> 16);
}

__device__ __forceinline__ void gload_lds16(const void* g, void* l) {
    auto gp = reinterpret_cast<__attribute__((address_space(1))) unsigned*>(
        reinterpret_cast<uintptr_t>(g));
    auto lp = reinterpret_cast<__attribute__((address_space(3))) unsigned*>(
        reinterpret_cast<uintptr_t>(l));
    __builtin_amdgcn_global_load_lds(gp, lp, 16, 0, 0);
}

// ---------------- fp32 -> bf16 cast ----------------
__global__ __launch_bounds__(256) void cvt_kernel(const float* __restrict__ in,
                                                  unsigned short* __restrict__ out, int n4) {
    int idx = blockIdx.x * 256 + threadIdx.x;
    int stride = gridDim.x * 256;
    for (int i = idx; i < n4; i += stride) {
        float4 v = ((const float4*)in)[i];
        u16x4 o;
        o.x = f2bf(v.x); o.y = f2bf(v.y); o.z = f2bf(v.z); o.w = f2bf(v.w);
        ((u16x4*)out)[i] = o;
    }
}

// ---------------- fp32 [R][C] -> bf16 [C][R] ----------------
__global__ __launch_bounds__(256) void transpose_cvt(const float* __restrict__ in,
                                                     unsigned short* __restrict__ out,
                                                     int R, int C) {
    __shared__ float t[32][33];
    int c0 = blockIdx.x * 32, r0 = blockIdx.y * 32;
    int tx = threadIdx.x, ty = threadIdx.y;
    for (int i = ty; i < 32; i += 8)
        t[i][tx] = in[(size_t)(r0 + i) * C + c0 + tx];
    __syncthreads();
    for (int i = ty; i < 32; i += 8)
        out[(size_t)(c0 + i) * R + r0 + tx] = f2bf(t[tx][i]);
}

// ---------------- pipelined 128x128 bf16 GEMM (triple-buffer, counted vmcnt, phase barrier) ----
// C[M][N] = A[M][K] @ Bt[N][K]^T. N%128==0, K%32==0, K>=96. M arbitrary (row-clamped).
// Epilogue: v = acc * (col<split ? scale : 1) + bias[col]; store bf16 or f32.
__global__ __launch_bounds__(256) void gemm128p(const unsigned short* __restrict__ A,
                                                const unsigned short* __restrict__ Bt,
                                                void* __restrict__ C,
                                                const float* __restrict__ bias,
                                                int M, int N, int K, float scale, int split,
                                                int c_f32) {
    __shared__ unsigned short lds[3][2][4096];  // 48 KiB: [buf][A/B][128*32]
    int ntx = N >> 7;
    int nwg = gridDim.x, bid = blockIdx.x, swz = bid;
    if ((nwg & 7) == 0) { int cpx = nwg >> 3; swz = (bid & 7) * cpx + (bid >> 3); }
    int m0 = (swz / ntx) << 7, n0 = (swz % ntx) << 7;
    int tid = threadIdx.x, lane = tid & 63, w = tid >> 6;
    int wm = w >> 1, wn = w & 1;
    int lr = lane & 15, lg = lane >> 4;
    int gq = lg ^ ((lr >> 1) & 3);
    int nkt = K >> 5;

    int arow = tid >> 2;
    int sgl = (tid & 3) ^ ((arow >> 1) & 3);  // inverse-swizzled global k-granule
    int ra0 = m0 + arow;      if (ra0 > M - 1) ra0 = M - 1;
    int ra1 = m0 + 64 + arow; if (ra1 > M - 1) ra1 = M - 1;
    const unsigned short* a0 = A + (size_t)ra0 * K + (sgl << 3);
    const unsigned short* a1 = A + (size_t)ra1 * K + (sgl << 3);
    const unsigned short* b0 = Bt + (size_t)(n0 + arow) * K + (sgl << 3);
    const unsigned short* b1 = Bt + (size_t)(n0 + 64 + arow) * K + (sgl << 3);

    f32x4 acc[4][4] = {};

#define ST_A128(bi, kt) do { \
        gload_lds16(a0 + ((kt) << 5), &lds[bi][0][w << 9]); \
        gload_lds16(a1 + ((kt) << 5), &lds[bi][0][2048 + (w << 9)]); } while (0)
#define ST_B128(bi, kt) do { \
        gload_lds16(b0 + ((kt) << 5), &lds[bi][1][w << 9]); \
        gload_lds16(b1 + ((kt) << 5), &lds[bi][1][2048 + (w << 9)]); } while (0)

    ST_A128(0, 0); ST_B128(0, 0);
    ST_A128(1, 1); ST_B128(1, 1);

    int buf = 0;
    for (int t = 0; t < nkt; ++t) {
        asm volatile("s_waitcnt vmcnt(4)" ::: "memory");
        __builtin_amdgcn_s_barrier();
        int st = t + 2; if (st >= nkt) st = nkt - 1;
        int sbuf = buf + 2; if (sbuf >= 3) sbuf -= 3;
        ST_A128(sbuf, st);
        ST_B128(sbuf, st);
        const unsigned short* pa = &lds[buf][0][((wm << 6) + lr) * 32 + (gq << 3)];
        const unsigned short* pb = &lds[buf][1][((wn << 6) + lr) * 32 + (gq << 3)];
        bf16x8 af[4], bfr[4];
#pragma unroll
        for (int nt = 0; nt < 4; nt++) bfr[nt] = *(const bf16x8*)(pb + nt * 512);
#pragma unroll
        for (int mt = 0; mt < 4; mt++) af[mt] = *(const bf16x8*)(pa + mt * 512);
        __builtin_amdgcn_s_barrier();
        __builtin_amdgcn_s_setprio(1);
#pragma unroll
        for (int mt = 0; mt < 4; mt++)
#pragma unroll
            for (int nt = 0; nt < 4; nt++)
                acc[mt][nt] = __builtin_amdgcn_mfma_f32_16x16x32_bf16(af[mt], bfr[nt], acc[mt][nt], 0, 0, 0);
        __builtin_amdgcn_s_setprio(0);
        buf++; if (buf == 3) buf = 0;
    }
#undef ST_A128
#undef ST_B128

#pragma unroll
    for (int mt = 0; mt < 4; mt++) {
#pragma unroll
        for (int nt = 0; nt < 4; nt++) {
            int col = n0 + (wn << 6) + (nt << 4) + lr;
            float sc = (col < split) ? scale : 1.0f;
            float bv = bias ? bias[col] : 0.0f;
#pragma unroll
            for (int r = 0; r < 4; r++) {
                int row = m0 + (wm << 6) + (mt << 4) + (lg << 2) + r;
                if (row < M) {
                    float v = acc[mt][nt][r] * sc + bv;
                    if (c_f32) ((float*)C)[(size_t)row * N + col] = v;
                    else       ((unsigned short*)C)[(size_t)row * N + col] = f2bf(v);
                }
            }
        }
    }
}

// ---------------- large bf16 GEMM: 256x256, triple-buffer + counted vmcnt + 2-phase interleave --
// Per K-tile: vmcnt(4); bar; {stageA; read B+A-lo; bar; 16 MFMA; bar}; {stageB; read A-hi; bar; 16 MFMA}
__global__ __launch_bounds__(512, 2) void gemm256(const unsigned short* __restrict__ A,
                                                  const unsigned short* __restrict__ Bt,
                                                  unsigned short* __restrict__ C,
                                                  int M, int N, int K) {
    __shared__ unsigned short lds[3][2][8192];  // 96 KiB
    int nkt = K >> 5;
    int ntx = N >> 8;
    int nwg = gridDim.x, bid = blockIdx.x, swz = bid;
    if ((nwg & 7) == 0) { int cpx = nwg >> 3; swz = (bid & 7) * cpx + (bid >> 3); }
    int m0 = (swz / ntx) << 8, n0 = (swz % ntx) << 8;
    int tid = threadIdx.x, lane = tid & 63, w = tid >> 6;
    int wm = w >> 2, wn = w & 3;
    int lr = lane & 15, lg = lane >> 4;
    int gq = lg ^ ((lr >> 1) & 3);

    int srow = tid >> 2;
    int sgl = (tid & 3) ^ ((srow >> 1) & 3);
    const unsigned short* a0 = A + (size_t)(m0 + srow) * K + (sgl << 3);
    const unsigned short* a1 = A + (size_t)(m0 + 128 + srow) * K + (sgl << 3);
    const unsigned short* b0 = Bt + (size_t)(n0 + srow) * K + (sgl << 3);
    const unsigned short* b1 = Bt + (size_t)(n0 + 128 + srow) * K + (sgl << 3);

    f32x4 acc[8][4] = {};

#define STAGE_A256(bufi, kt) do { \
        gload_lds16(a0 + ((kt) << 5), &lds[bufi][0][w << 9]); \
        gload_lds16(a1 + ((kt) << 5), &lds[bufi][0][4096 + (w << 9)]); } while (0)
#define STAGE_B256(bufi, kt) do { \
        gload_lds16(b0 + ((kt) << 5), &lds[bufi][1][w << 9]); \
        gload_lds16(b1 + ((kt) << 5), &lds[bufi][1][4096 + (w << 9)]); } while (0)

    STAGE_A256(0, 0); STAGE_B256(0, 0);
    STAGE_A256(1, 1); STAGE_B256(1, 1);

    int buf = 0;
    for (int t = 0; t < nkt; ++t) {
        asm volatile("s_waitcnt vmcnt(4)" ::: "memory");
        __builtin_amdgcn_s_barrier();
        int st = t + 2; if (st >= nkt) st = nkt - 1;
        int sbuf = buf + 2; if (sbuf >= 3) sbuf -= 3;

        const unsigned short* pa = &lds[buf][0][((wm << 7) + lr) * 32 + (gq << 3)];
        const unsigned short* pb = &lds[buf][1][((wn << 6) + lr) * 32 + (gq << 3)];

        // phase 1: stage A(t+2); read B-frags + A rows 0..63 of wave half; 16 MFMA
        STAGE_A256(sbuf, st);
        bf16x8 bfr[4], af[4];
#pragma unroll
        for (int nt = 0; nt < 4; nt++) bfr[nt] = *(const bf16x8*)(pb + nt * 512);
#pragma unroll
        for (int mt = 0; mt < 4; mt++) af[mt] = *(const bf16x8*)(pa + mt * 512);
        __builtin_amdgcn_s_barrier();
        __builtin_amdgcn_s_setprio(1);
#pragma unroll
        for (int mt = 0; mt < 4; mt++)
#pragma unroll
            for (int nt = 0; nt < 4; nt++)
                acc[mt][nt] = __builtin_amdgcn_mfma_f32_16x16x32_bf16(af[mt], bfr[nt], acc[mt][nt], 0, 0, 0);
        __builtin_amdgcn_s_setprio(0);
        __builtin_amdgcn_s_barrier();

        // phase 2: stage B(t+2); read A rows 64..127 of wave half; 16 MFMA
        STAGE_B256(sbuf, st);
        bf16x8 ag[4];
#pragma unroll
        for (int mt = 0; mt < 4; mt++) ag[mt] = *(const bf16x8*)(pa + (mt + 4) * 512);
        __builtin_amdgcn_s_barrier();
        __builtin_amdgcn_s_setprio(1);
#pragma unroll
        for (int mt = 0; mt < 4; mt++)
#pragma unroll
            for (int nt = 0; nt < 4; nt++)
                acc[mt + 4][nt] = __builtin_amdgcn_mfma_f32_16x16x32_bf16(ag[mt], bfr[nt], acc[mt + 4][nt], 0, 0, 0);
        __builtin_amdgcn_s_setprio(0);

        buf++; if (buf == 3) buf = 0;
    }
#undef STAGE_A256
#undef STAGE_B256

#pragma unroll
    for (int mt = 0; mt < 8; mt++) {
#pragma unroll
        for (int nt = 0; nt < 4; nt++) {
            int col = n0 + (wn << 6) + (nt << 4) + lr;
            size_t rbase = (size_t)(m0 + (wm << 7) + (mt << 4) + (lg << 2));
#pragma unroll
            for (int r = 0; r < 4; r++)
                C[(rbase + r) * N + col] = f2bf(acc[mt][nt][r]);
        }
    }
}

// ---------------- fused flash attention over 1088 keys (1024 media + 64 latent) ----------------
// T14: next tile's K/V global loads issued before compute of current tile.
__global__ __launch_bounds__(256) void attn_kernel(const unsigned short* __restrict__ qg, int qstride,
                                                   const unsigned short* __restrict__ kvg,
                                                   const unsigned short* __restrict__ lkvg, int lstride,
                                                   unsigned short* __restrict__ og) {
    __shared__ unsigned short K_lds[64 * 72];
    __shared__ unsigned short V_lds[64 * 72];
    __shared__ unsigned short P_lds[4][16 * 72];
    int bm = blockIdx.x >> 4, h = blockIdx.x & 15;
    int tid = threadIdx.x, lane = tid & 63, w = tid >> 6;
    int lr = lane & 15, lg = lane >> 4;

    bf16x8 qf[2];
#pragma unroll
    for (int kk = 0; kk < 2; kk++)
        qf[kk] = *(const bf16x8*)(qg + (size_t)((w << 4) + lr) * qstride + (h << 6) + (kk << 5) + (lg << 3));

    f32x4 acc[4] = {};
    float m_run[4], l_run[4];
#pragma unroll
    for (int r = 0; r < 4; r++) { m_run[r] = -1e30f; l_run[r] = 0.0f; }

    int jrow = tid >> 2;
    int seg = (tid & 3) << 4;

    const unsigned short* s0 = kvg + (size_t)((bm << 10) + jrow) * 2048 + (h << 6);
    u16x8 k0 = *(const u16x8*)(s0 + seg);
    u16x8 k1 = *(const u16x8*)(s0 + seg + 8);
    u16x8 v0 = *(const u16x8*)(s0 + 1024 + seg);
    u16x8 v1 = *(const u16x8*)(s0 + 1024 + seg + 8);

    for (int t = 0; t < 17; t++) {
        *(u16x8*)(&K_lds[jrow * 72 + seg]) = k0;
        *(u16x8*)(&K_lds[jrow * 72 + seg + 8]) = k1;
#pragma unroll
        for (int c = 0; c < 8; c++) V_lds[(seg + c) * 72 + jrow] = v0[c];
#pragma unroll
        for (int c = 0; c < 8; c++) V_lds[(seg + 8 + c) * 72 + jrow] = v1[c];
        __syncthreads();

        // prefetch next tile (hides HBM latency under QK/softmax/PV)
        u16x8 nk0 = k0, nk1 = k1, nv0 = v0, nv1 = v1;
        if (t < 16) {
            const unsigned short* src = (t < 15)
                ? kvg + (size_t)((bm << 10) + ((t + 1) << 6) + jrow) * 2048 + (h << 6)
                : lkvg + (size_t)jrow * lstride + (h << 6);
            nk0 = *(const u16x8*)(src + seg);
            nk1 = *(const u16x8*)(src + seg + 8);
            nv0 = *(const u16x8*)(src + 1024 + seg);
            nv1 = *(const u16x8*)(src + 1024 + seg + 8);
        }

        f32x4 s[4] = {};
#pragma unroll
        for (int jt = 0; jt < 4; jt++) {
#pragma unroll
            for (int kk = 0; kk < 2; kk++) {
                bf16x8 kf = *(const bf16x8*)(&K_lds[(size_t)((jt << 4) + lr) * 72 + (kk << 5) + (lg << 3)]);
                s[jt] = __builtin_amdgcn_mfma_f32_16x16x32_bf16(qf[kk], kf, s[jt], 0, 0, 0);
            }
        }
#pragma unroll
        for (int r = 0; r < 4; r++) {
            float mx = fmaxf(fmaxf(s[0][r], s[1][r]), fmaxf(s[2][r], s[3][r]));
            mx = fmaxf(mx, __shfl_xor(mx, 1));
            mx = fmaxf(mx, __shfl_xor(mx, 2));
            mx = fmaxf(mx, __shfl_xor(mx, 4));
            mx = fmaxf(mx, __shfl_xor(mx, 8));
            float nm = fmaxf(m_run[r], mx);
            float fct = __expf(m_run[r] - nm);
            m_run[r] = nm;
            float p0 = __expf(s[0][r] - nm);
            float p1 = __expf(s[1][r] - nm);
            float p2 = __expf(s[2][r] - nm);
            float p3 = __expf(s[3][r] - nm);
            float sum = p0 + p1 + p2 + p3;
            sum += __shfl_xor(sum, 1);
            sum += __shfl_xor(sum, 2);
            sum += __shfl_xor(sum, 4);
            sum += __shfl_xor(sum, 8);
            l_run[r] = l_run[r] * fct + sum;
#pragma unroll
            for (int dt = 0; dt < 4; dt++) acc[dt][r] *= fct;
            int prow = ((lg << 2) + r) * 72;
            P_lds[w][prow + lr]      = f2bf(p0);
            P_lds[w][prow + 16 + lr] = f2bf(p1);
            P_lds[w][prow + 32 + lr] = f2bf(p2);
            P_lds[w][prow + 48 + lr] = f2bf(p3);
        }
#pragma unroll
        for (int jkk = 0; jkk < 2; jkk++) {
            bf16x8 pf = *(const bf16x8*)(&P_lds[w][(size_t)lr * 72 + (jkk << 5) + (lg << 3)]);
#pragma unroll
            for (int dt = 0; dt < 4; dt++) {
                bf16x8 vf = *(const bf16x8*)(&V_lds[(size_t)((dt << 4) + lr) * 72 + (jkk << 5) + (lg << 3)]);
                acc[dt] = __builtin_amdgcn_mfma_f32_16x16x32_bf16(pf, vf, acc[dt], 0, 0, 0);
            }
        }
        __syncthreads();
        k0 = nk0; k1 = nk1; v0 = nv0; v1 = nv1;
    }
#pragma unroll
    for (int dt = 0; dt < 4; dt++) {
#pragma unroll
        for (int r = 0; r < 4; r++) {
            int i = (w << 4) + (lg << 2) + r;
            float v = acc[dt][r] / l_run[r];
            og[(size_t)((bm << 6) + i) * 1024 + (h << 6) + (dt << 4) + lr] = f2bf(v);
        }
    }
}

extern "C" void kernel_launch(void* const* d_in, const int* in_sizes, int n_in,
                              void* d_out, int out_size, void* d_ws, size_t ws_size,
                              hipStream_t stream) {
    const float* x       = (const float*)d_in[0];
    const float* latents = (const float*)d_in[1];
    const float* Wq      = (const float*)d_in[2];
    const float* Wkv     = (const float*)d_in[3];
    const float* Wout    = (const float*)d_in[4];
    const float* bout    = (const float*)d_in[5];
    char* ws = (char*)d_ws;
    unsigned short* xb    = (unsigned short*)(ws);                 // 64 MiB  [32768][1024]
    unsigned short* kvb   = (unsigned short*)(ws + 67108864);      // 128 MiB [32768][2048]
    unsigned short* wqkvt = (unsigned short*)(ws + 201326592);     // 6 MiB   [3072][1024] (Wq^T | Wkv^T)
    unsigned short* wkvt  = wqkvt + 1024 * 1024;                   //         rows 1024..3071
    unsigned short* woutt = (unsigned short*)(ws + 207618048);     // 2 MiB   [1024][1024]
    unsigned short* latb  = (unsigned short*)(ws + 209715200);     // 128 KiB [64][1024]
    unsigned short* qlkvb = (unsigned short*)(ws + 209846272);     // 384 KiB [64][3072] (q | lk | lv)
    unsigned short* attnb = (unsigned short*)(ws + 210239488);     // 4 MiB   [2048][1024]

    cvt_kernel<<<2048, 256, 0, stream>>>(x, xb, 33554432 / 4);
    cvt_kernel<<<64, 256, 0, stream>>>(latents, latb, 65536 / 4);
    dim3 tb(32, 8);
    transpose_cvt<<<dim3(32, 32), tb, 0, stream>>>(Wq, wqkvt, 1024, 1024);
    transpose_cvt<<<dim3(64, 32), tb, 0, stream>>>(Wkv, wkvt, 1024, 2048);
    transpose_cvt<<<dim3(32, 32), tb, 0, stream>>>(Wout, woutt, 1024, 1024);
    // [q | lkv] = latents @ [Wq | Wkv]; q-part (cols<1024) scaled by dh^-0.5
    gemm128p<<<24, 256, 0, stream>>>(latb, wqkvt, qlkvb, nullptr, 64, 3072, 1024, 0.125f, 1024, 0);
    // kv = x @ Wkv  (dominant GEMM)
    gemm256<<<1024, 512, 0, stream>>>(xb, wkvt, kvb, 32768, 2048, 1024);
    // fused attention: q rows stride 3072; latent kv at qlkvb+1024, stride 3072
    attn_kernel<<<512, 256, 0, stream>>>(qlkvb, 3072, kvb, qlkvb + 1024, 3072, attnb);
    // out = attnout @ Wout + bout (fp32 out)
    gemm128p<<<128, 256, 0, stream>>>(attnb, woutt, (void*)d_out, bout, 2048, 1024, 1024, 1.0f, 0, 1);
}